// Round 8
// baseline (476.624 us; speedup 1.0000x reference)
//
#include <hip/hip_runtime.h>
#include <math.h>

#define NC    512
#define NG    4
#define NCG   128          // C / G
#define NR    16           // reduced dim
#define NTOPK 384
#define NB    16
#define HW    (112 * 112)  // 12544
#define ALPHA 0.1f
#define EPSC  1e-8f

typedef float f32x4 __attribute__((ext_vector_type(4)));

#define AL(p)    __hip_atomic_load((p), __ATOMIC_RELAXED, __HIP_MEMORY_SCOPE_AGENT)
#define ASR(p,v) __hip_atomic_store((p), (v), __ATOMIC_RELAXED, __HIP_MEMORY_SCOPE_AGENT)

// ---- register tile: 3136 f32x4 per (b,c); thread t owns j*256+t (+tail) ----
__device__ __forceinline__ void load_tile(f32x4* __restrict__ buf,
                                          const float* __restrict__ base, int t) {
  const f32x4* p = reinterpret_cast<const f32x4*>(base);
  #pragma unroll
  for (int j = 0; j < 12; ++j)
    buf[j] = __builtin_nontemporal_load(&p[t + 256 * j]);
  if (t < 64) buf[12] = __builtin_nontemporal_load(&p[3072 + t]);
}

__device__ __forceinline__ void store_tile(const f32x4* __restrict__ buf, float bl,
                                           float* __restrict__ base, int t) {
  f32x4* q = reinterpret_cast<f32x4*>(base);
  #pragma unroll
  for (int j = 0; j < 12; ++j)
    __builtin_nontemporal_store(buf[j] * bl, &q[t + 256 * j]);
  if (t < 64) __builtin_nontemporal_store(buf[12] * bl, &q[3072 + t]);
}

// ---- reduce tile -> (sum,max), t0 posts to ws (agent-scope) ----
__device__ __forceinline__ void reduce_store(const f32x4* __restrict__ buf, int t,
                                             int b, int c, float* red_s,
                                             float* red_m, float* __restrict__ ws_s,
                                             float* __restrict__ ws_m) {
  float s = 0.f, m = -INFINITY;
  #pragma unroll
  for (int j = 0; j < 12; ++j) {
    f32x4 v = buf[j];
    s += (v.x + v.y) + (v.z + v.w);
    m = fmaxf(m, fmaxf(fmaxf(v.x, v.y), fmaxf(v.z, v.w)));
  }
  if (t < 64) {
    f32x4 v = buf[12];
    s += (v.x + v.y) + (v.z + v.w);
    m = fmaxf(m, fmaxf(fmaxf(v.x, v.y), fmaxf(v.z, v.w)));
  }
  #pragma unroll
  for (int off = 32; off; off >>= 1) {
    s += __shfl_down(s, off, 64);
    m = fmaxf(m, __shfl_down(m, off, 64));
  }
  if ((t & 63) == 0) { red_s[t >> 6] = s; red_m[t >> 6] = m; }
  __syncthreads();
  if (t == 0) {
    float st = (red_s[0] + red_s[1]) + (red_s[2] + red_s[3]);
    float mt = fmaxf(fmaxf(red_m[0], red_m[1]), fmaxf(red_m[2], red_m[3]));
    ASR(&ws_s[b * NC + c], st);
    ASR(&ws_m[b * NC + c], mt);
  }
  __syncthreads();
}

// ---- hierarchical grid barrier: 8 groups x 64 blocks, per-group go flags ----
// bar layout (uint, 128B-separated lines): grp_cnt[g]=bar[g*32], root=bar[256],
// go[g]=bar[288+g*32]. Epochs monotonically increase; init kernel zeroes.
__device__ __forceinline__ void barrier_sync(unsigned epoch, unsigned* bar,
                                             int grp, int t) {
  __syncthreads();
  if (t == 0) {
    unsigned a = __hip_atomic_fetch_add(&bar[grp * 32], 1u, __ATOMIC_ACQ_REL,
                                        __HIP_MEMORY_SCOPE_AGENT);
    if (a == 63u) {  // group leader (last of 64)
      unsigned r = __hip_atomic_fetch_add(&bar[256], 1u, __ATOMIC_ACQ_REL,
                                          __HIP_MEMORY_SCOPE_AGENT);
      if (r == 7u) {  // global last: reset, then broadcast go
        ASR(&bar[256], 0u);
        #pragma unroll
        for (int g = 0; g < 8; ++g) ASR(&bar[g * 32], 0u);
        #pragma unroll
        for (int g = 0; g < 8; ++g)
          __hip_atomic_store(&bar[288 + g * 32], epoch, __ATOMIC_RELEASE,
                             __HIP_MEMORY_SCOPE_AGENT);
      }
    }
    while (__hip_atomic_load(&bar[288 + grp * 32], __ATOMIC_ACQUIRE,
                             __HIP_MEMORY_SCOPE_AGENT) < epoch)
      __builtin_amdgcn_s_sleep(1);
  }
  __syncthreads();
}

// ---- per-batch mask pipeline (verified in R5): returns blend(b, c) ----
__device__ __forceinline__ float compute_blend(
    int b, int c, int t, const float* __restrict__ W1,
    const float* __restrict__ bias1, const float* __restrict__ W2,
    const float* __restrict__ bias2, const float* __restrict__ noise_u,
    const float* __restrict__ ws_s, const float* __restrict__ ws_m,
    float* comb, float* sc, float* h, int* red_i, float* bl_sh) {
  __syncthreads();  // protect LDS reuse from previous call
  #pragma unroll
  for (int q = 0; q < 2; ++q) {
    const int cc = t + q * 256;
    comb[cc]      = AL(&ws_s[b * NC + cc]) * (1.0f / (float)HW);
    comb[NC + cc] = AL(&ws_m[b * NC + cc]);
  }
  __syncthreads();
  {  // MLP1: 64 outputs, 4 threads each
    const int pair = t >> 2, sub = t & 3;
    const int g = pair >> 4, r = pair & 15;
    const float* cf = comb + g * (2 * NCG);
    const float* w  = W1 + (size_t)g * (2 * NCG) * NR + r;
    const int i0 = sub * 64;
    float acc = 0.f;
    #pragma unroll 8
    for (int i = 0; i < 64; ++i) acc += cf[i0 + i] * w[(i0 + i) * NR];
    acc += __shfl_down(acc, 2, 4);
    acc += __shfl_down(acc, 1, 4);
    if (sub == 0) h[pair] = fmaxf(acc + bias1[g * NR + r], 0.f);
  }
  __syncthreads();
  #pragma unroll
  for (int cc = 0; cc < 2; ++cc) {  // MLP2: 512 scores
    const int ch = t + cc * 256;
    const int g = ch >> 7, o = ch & 127;
    float acc = bias2[g * NCG + o];
    const float* w  = W2 + (size_t)g * NR * NCG + o;
    const float* hh = h + g * NR;
    #pragma unroll
    for (int r = 0; r < NR; ++r) acc += hh[r] * w[r * NCG];
    sc[ch] = acc;
  }
  __syncthreads();
  // exact rank of channel c (stable lowest-index tie-break)
  const float my = sc[c];
  int cnt = 0;
  { float v = sc[t];       cnt += (v > my) || (v == my && t < c); }
  { float v = sc[t + 256]; cnt += (v > my) || (v == my && (t + 256) < c); }
  #pragma unroll
  for (int off = 32; off; off >>= 1) cnt += __shfl_down(cnt, off, 64);
  if ((t & 63) == 0) red_i[t >> 6] = cnt;
  __syncthreads();
  if (t == 0) {
    const int ct = red_i[0] + red_i[1] + red_i[2] + red_i[3];
    const float hard = (ct < NTOPK) ? 1.f : 0.f;
    const float u = noise_u[b * NC + c];
    const float gum = -logf(-logf(u + EPSC) + EPSC);
    const float soft = 1.f / (1.f + expf(-(my + gum) * 2.0f));  // TAU=0.5
    const float mask = hard * soft;
    *bl_sh = mask + (1.f - mask) * ALPHA;
  }
  __syncthreads();
  return *bl_sh;
}

__global__ void init_bar_kernel(unsigned* bar) {
  for (int i = threadIdx.x; i < 544; i += 256) bar[i] = 0u;
}

// Persistent single-read kernel: block = channel, 4-deep batch pipeline.
// x is read ONCE (411 MB) and written once (411 MB): 822 MB total HBM.
__global__ __launch_bounds__(256, 2) void mega2_kernel(
    const float* __restrict__ x, const float* __restrict__ W1,
    const float* __restrict__ bias1, const float* __restrict__ W2,
    const float* __restrict__ bias2, const float* __restrict__ noise_u,
    float* __restrict__ out, unsigned* __restrict__ bar,
    float* __restrict__ ws_s, float* __restrict__ ws_m) {
  const int c = blockIdx.x;
  const int t = threadIdx.x;
  const int grp = c & 7;

  __shared__ float comb[2 * NC];
  __shared__ float sc[NC];
  __shared__ float h[NG * NR];
  __shared__ float red_s[4], red_m[4];
  __shared__ int   red_i[4];
  __shared__ float bl_sh;

  f32x4 B0[13], B1[13], B2[13], B3[13];

  // prologue: load + reduce batches 0..3, publish sums, barrier 1
  load_tile(B0, x + ((size_t)(0 * NC + c)) * HW, t);
  load_tile(B1, x + ((size_t)(1 * NC + c)) * HW, t);
  load_tile(B2, x + ((size_t)(2 * NC + c)) * HW, t);
  load_tile(B3, x + ((size_t)(3 * NC + c)) * HW, t);
  reduce_store(B0, t, 0, c, red_s, red_m, ws_s, ws_m);
  reduce_store(B1, t, 1, c, red_s, red_m, ws_s, ws_m);
  reduce_store(B2, t, 2, c, red_s, red_m, ws_s, ws_m);
  reduce_store(B3, t, 3, c, red_s, red_m, ws_s, ws_m);
  barrier_sync(1u, bar, grp, t);

  for (int p = 0; p < 4; ++p) {
    const int base = 4 * p;
    float bl;
    bl = compute_blend(base + 0, c, t, W1, bias1, W2, bias2, noise_u, ws_s,
                       ws_m, comb, sc, h, red_i, &bl_sh);
    store_tile(B0, bl, out + ((size_t)((base + 0) * NC + c)) * HW, t);
    bl = compute_blend(base + 1, c, t, W1, bias1, W2, bias2, noise_u, ws_s,
                       ws_m, comb, sc, h, red_i, &bl_sh);
    store_tile(B1, bl, out + ((size_t)((base + 1) * NC + c)) * HW, t);
    bl = compute_blend(base + 2, c, t, W1, bias1, W2, bias2, noise_u, ws_s,
                       ws_m, comb, sc, h, red_i, &bl_sh);
    store_tile(B2, bl, out + ((size_t)((base + 2) * NC + c)) * HW, t);
    bl = compute_blend(base + 3, c, t, W1, bias1, W2, bias2, noise_u, ws_s,
                       ws_m, comb, sc, h, red_i, &bl_sh);
    store_tile(B3, bl, out + ((size_t)((base + 3) * NC + c)) * HW, t);

    if (p < 3) {
      load_tile(B0, x + ((size_t)((base + 4) * NC + c)) * HW, t);
      load_tile(B1, x + ((size_t)((base + 5) * NC + c)) * HW, t);
      load_tile(B2, x + ((size_t)((base + 6) * NC + c)) * HW, t);
      load_tile(B3, x + ((size_t)((base + 7) * NC + c)) * HW, t);
      reduce_store(B0, t, base + 4, c, red_s, red_m, ws_s, ws_m);
      reduce_store(B1, t, base + 5, c, red_s, red_m, ws_s, ws_m);
      reduce_store(B2, t, base + 6, c, red_s, red_m, ws_s, ws_m);
      reduce_store(B3, t, base + 7, c, red_s, red_m, ws_s, ws_m);
      barrier_sync((unsigned)(p + 2), bar, grp, t);
    }
  }
}

extern "C" void kernel_launch(void* const* d_in, const int* in_sizes, int n_in,
                              void* d_out, int out_size, void* d_ws, size_t ws_size,
                              hipStream_t stream) {
  const float* x       = (const float*)d_in[0];
  const float* W1      = (const float*)d_in[1];
  const float* b1      = (const float*)d_in[2];
  const float* W2      = (const float*)d_in[3];
  const float* b2      = (const float*)d_in[4];
  const float* noise_u = (const float*)d_in[5];
  float* out = (float*)d_out;

  unsigned* bar = (unsigned*)d_ws;                    // 544 uints (barrier)
  float* ws_s = (float*)((char*)d_ws + 4096);         // [16][512]
  float* ws_m = ws_s + NB * NC;                       // [16][512]

  init_bar_kernel<<<1, 256, 0, stream>>>(bar);
  mega2_kernel<<<NC, 256, 0, stream>>>(x, W1, b1, W2, b2, noise_u, out,
                                       bar, ws_s, ws_m);
}

// Round 9
// 217.941 us; speedup vs baseline: 2.1869x; 2.1869x over previous
//
#include <hip/hip_runtime.h>
#include <math.h>

#define NC    512
#define NG    4
#define NCG   128          // C / G
#define NR    16           // reduced dim
#define NTOPK 384
#define NB    16
#define HW    (112 * 112)  // 12544
#define ALPHA 0.1f
#define EPSC  1e-8f

typedef float f32x4 __attribute__((ext_vector_type(4)));

// ---------------- Kernel 1: per-(b,c) avg + max pooling ----------------
// Forward order bc = 0..8191. Cached loads leave the tail of x hot in L3 for
// the reversed fused kernel (palindrome traversal across the two passes).
__global__ __launch_bounds__(256) void pool_kernel(
    const float* __restrict__ x, float* __restrict__ avg_out,
    float* __restrict__ max_out) {
  const int bc = blockIdx.x;  // b*C + c
  const f32x4* p = reinterpret_cast<const f32x4*>(x + (size_t)bc * HW);
  float s = 0.f;
  float m = -INFINITY;
  // 3136 = 3*1024 + 64
  for (int i = threadIdx.x; i < 3072; i += 1024) {
    f32x4 v0 = p[i];
    f32x4 v1 = p[i + 256];
    f32x4 v2 = p[i + 512];
    f32x4 v3 = p[i + 768];
    s += (v0.x + v0.y) + (v0.z + v0.w);
    s += (v1.x + v1.y) + (v1.z + v1.w);
    s += (v2.x + v2.y) + (v2.z + v2.w);
    s += (v3.x + v3.y) + (v3.z + v3.w);
    m = fmaxf(m, fmaxf(fmaxf(v0.x, v0.y), fmaxf(v0.z, v0.w)));
    m = fmaxf(m, fmaxf(fmaxf(v1.x, v1.y), fmaxf(v1.z, v1.w)));
    m = fmaxf(m, fmaxf(fmaxf(v2.x, v2.y), fmaxf(v2.z, v2.w)));
    m = fmaxf(m, fmaxf(fmaxf(v3.x, v3.y), fmaxf(v3.z, v3.w)));
  }
  if (threadIdx.x < 64) {
    f32x4 v = p[3072 + threadIdx.x];
    s += (v.x + v.y) + (v.z + v.w);
    m = fmaxf(m, fmaxf(fmaxf(v.x, v.y), fmaxf(v.z, v.w)));
  }
  #pragma unroll
  for (int off = 32; off > 0; off >>= 1) {
    s += __shfl_down(s, off, 64);
    m = fmaxf(m, __shfl_down(m, off, 64));
  }
  __shared__ float ss[4], sm[4];
  const int wave = threadIdx.x >> 6;
  const int lane = threadIdx.x & 63;
  if (lane == 0) { ss[wave] = s; sm[wave] = m; }
  __syncthreads();
  if (threadIdx.x == 0) {
    float st = (ss[0] + ss[1]) + (ss[2] + ss[3]);
    float mt = fmaxf(fmaxf(sm[0], sm[1]), fmaxf(sm[2], sm[3]));
    avg_out[bc] = st / (float)HW;
    max_out[bc] = mt;
  }
}

// -------- Kernel 2: fused mask-compute + scale --------
// 2048 blocks x 256 thr. Reversed block rb owns 4 channels of one batch:
// b = rb>>7, c0 = (rb&127)*4. Prologue recomputes the per-batch mask
// pipeline (deterministic, identical across the 128 blocks of a batch),
// keeps 4 blend values in LDS, then streams 4 tiles LIFO (descending bc):
// reads the tail of x first (freshest in L3 after pool), ends at the head
// (hot for the next replay's pool).
__global__ __launch_bounds__(256) void fused_kernel(
    const float* __restrict__ x, const float* __restrict__ avg,
    const float* __restrict__ mx, const float* __restrict__ W1,
    const float* __restrict__ b1, const float* __restrict__ W2,
    const float* __restrict__ b2, const float* __restrict__ noise_u,
    float* __restrict__ out) {
  const int rb = 2047 - (int)blockIdx.x;  // reversed: tail blocks first
  const int b  = rb >> 7;                 // 128 blocks per batch
  const int c0 = (rb & 127) * 4;          // this block's 4 channels
  const int t  = threadIdx.x;

  __shared__ float comb[2 * NC];   // [avg(512) | max(512)]
  __shared__ float h[NG * NR];     // 64
  __shared__ float sc[NC];         // 512
  __shared__ float blend_loc[4];

  // ---- load pooled features for batch b (coalesced) ----
  {
    const float* pa = avg + b * NC;
    const float* pm = mx  + b * NC;
    comb[t]             = pa[t];
    comb[t + 256]       = pa[t + 256];
    comb[512 + t]       = pm[t];
    comb[512 + t + 256] = pm[t + 256];
  }
  __syncthreads();

  // ---- MLP1: 64 outputs, 4 threads each (64 MACs + shfl4 reduce) ----
  {
    const int pair = t >> 2, sub = t & 3;   // pair in [0,64)
    const int g = pair >> 4, r = pair & 15;
    const float* cf = comb + g * (2 * NCG);        // 256 inputs for group g
    const float* w  = W1 + (size_t)g * (2 * NCG) * NR + r;  // stride NR
    const int i0 = sub * 64;
    float acc = 0.f;
    #pragma unroll 8
    for (int i = 0; i < 64; ++i) acc += cf[i0 + i] * w[(i0 + i) * NR];
    acc += __shfl_down(acc, 2, 4);
    acc += __shfl_down(acc, 1, 4);
    if (sub == 0) h[pair] = fmaxf(acc + b1[g * NR + r], 0.f);
  }
  __syncthreads();

  // ---- MLP2: 512 scores, 2 per thread ----
  #pragma unroll
  for (int cc = 0; cc < 2; ++cc) {
    const int c = t + cc * 256;
    const int g = c >> 7, o = c & 127;
    float acc = b2[g * NCG + o];
    const float* w  = W2 + (size_t)g * NR * NCG + o;  // stride NCG
    const float* hh = h + g * NR;
    #pragma unroll
    for (int r = 0; r < NR; ++r) acc += hh[r] * w[r * NCG];
    sc[c] = acc;
  }
  __syncthreads();

  // ---- exact rank-count for our 4 channels (64 threads per channel) ----
  {
    const int ci = t >> 6, sub = t & 63;
    const int c = c0 + ci;
    const float my = sc[c];
    int cnt = 0;
    const int j0 = sub * 8;
    #pragma unroll
    for (int jj = 0; jj < 8; ++jj) {
      const int j = j0 + jj;
      const float v = sc[j];
      cnt += (v > my) || (v == my && j < c);
    }
    #pragma unroll
    for (int off = 32; off > 0; off >>= 1) cnt += __shfl_down(cnt, off, 64);
    if (sub == 0) {
      const float hard = (cnt < NTOPK) ? 1.f : 0.f;
      const float u = noise_u[b * NC + c];
      const float gum = -logf(-logf(u + EPSC) + EPSC);
      const float soft = 1.f / (1.f + expf(-(my + gum) * 2.0f));  // TAU=0.5
      const float mask = hard * soft;
      blend_loc[ci] = mask + (1.f - mask) * ALPHA;
    }
  }
  __syncthreads();

  // ---- scale the 4 owned tiles, LIFO order (descending bc) ----
  for (int k = 3; k >= 0; --k) {
    const int bc = (b * NC) + c0 + k;
    const float s = blend_loc[k];
    const f32x4* p = reinterpret_cast<const f32x4*>(x + (size_t)bc * HW);
    f32x4* q = reinterpret_cast<f32x4*>(out + (size_t)bc * HW);
    for (int i = t; i < 3072; i += 1024) {
      f32x4 v0 = p[i];
      f32x4 v1 = p[i + 256];
      f32x4 v2 = p[i + 512];
      f32x4 v3 = p[i + 768];
      v0 *= s; v1 *= s; v2 *= s; v3 *= s;
      __builtin_nontemporal_store(v0, &q[i]);
      __builtin_nontemporal_store(v1, &q[i + 256]);
      __builtin_nontemporal_store(v2, &q[i + 512]);
      __builtin_nontemporal_store(v3, &q[i + 768]);
    }
    if (t < 64) {
      const int i = 3072 + t;
      f32x4 v = p[i];
      v *= s;
      __builtin_nontemporal_store(v, &q[i]);
    }
  }
}

extern "C" void kernel_launch(void* const* d_in, const int* in_sizes, int n_in,
                              void* d_out, int out_size, void* d_ws, size_t ws_size,
                              hipStream_t stream) {
  const float* x       = (const float*)d_in[0];
  const float* W1      = (const float*)d_in[1];
  const float* b1      = (const float*)d_in[2];
  const float* W2      = (const float*)d_in[3];
  const float* b2      = (const float*)d_in[4];
  const float* noise_u = (const float*)d_in[5];
  float* out = (float*)d_out;

  float* ws_avg = (float*)d_ws;        // B*C floats
  float* ws_max = ws_avg + NB * NC;    // B*C floats

  pool_kernel<<<NB * NC, 256, 0, stream>>>(x, ws_avg, ws_max);
  fused_kernel<<<2048, 256, 0, stream>>>(x, ws_avg, ws_max, W1, b1, W2, b2,
                                         noise_u, out);
}